// Round 1
// baseline (412.025 us; speedup 1.0000x reference)
//
#include <hip/hip_runtime.h>

// Quaternion normalization: x (65536 x 1024 fp32) viewed as groups of 4
// consecutive floats; each group divided by its L2 norm (norm==0 -> 1.0).
// Memory-bound streaming kernel: 1 thread = 1 quaternion = one float4
// load + one float4 store (16 B/lane, ideal coalescing).

__global__ __launch_bounds__(256) void quat_normalize_kernel(
    const float4* __restrict__ x, float4* __restrict__ out, int n_quats) {
    int i = blockIdx.x * blockDim.x + threadIdx.x;
    if (i >= n_quats) return;
    float4 v = x[i];
    float s = v.x * v.x + v.y * v.y + v.z * v.z + v.w * v.w;
    // reference: norm==0 replaced by 1.0 (so zero vectors pass through as zero)
    float r = (s == 0.0f) ? 1.0f : rsqrtf(s);
    v.x *= r;
    v.y *= r;
    v.z *= r;
    v.w *= r;
    out[i] = v;
}

extern "C" void kernel_launch(void* const* d_in, const int* in_sizes, int n_in,
                              void* d_out, int out_size, void* d_ws, size_t ws_size,
                              hipStream_t stream) {
    const float4* x = (const float4*)d_in[0];
    float4* out = (float4*)d_out;
    int n_quats = in_sizes[0] / 4;  // 65536 * 1024 / 4 = 16,777,216
    const int block = 256;
    int grid = (n_quats + block - 1) / block;
    quat_normalize_kernel<<<grid, block, 0, stream>>>(x, out, n_quats);
}